// Round 1
// 66.206 us; speedup vs baseline: 1.0742x; 1.0742x over previous
//
#include <hip/hip_runtime.h>

// HistogramLoss: total = emd(hist(rgb_in),hist(rgb_ref)) + emd(hist(yuv_in),hist(yuv_ref))
// emd collapses to sum_k (64-k)*(h1_k - h2_k); bins tile [-0.05,1.05] disjointly.
//
// R4: all-f32 hl_partial. Rationale: the jax reference is f32 end-to-end
// (f32 centers, f32 (img+1)*0.5, f32 width-|u-c|, f32 einsum), and the
// previous f64 kernel's t>0 decision passed at absmax 2.44e-4 -> the
// effective inclusion boundary is t>0 to ~1e-9. We recast the per-bin test
// into bin coordinates: g = (u+0.05)/step - 0.5; candidate bins k0=floor(g),
// k0+1; window membership is frac(g) vs 0.5. Boundary error vs ref's f32
// expression ~2e-7 in u (bin width 1.7e-2) -> ~tens of +/-1-weight
// adjacent-bin flips that largely cancel between the two images.
// This removes ALL f64 VALU (half-rate, 2-slot), all f64<->f32 cvts, and the
// per-candidate LDS centers reads (24 conflicted ds_read_b32/pixel).
// Integer weight part stays exact: f32 holds integers < 2^24 exactly
// (per-thread <= 1536, block <= 393216). Soft part expm1(L*t) ~ z + z^2/2.
// Loads widened to float2 (2 adjacent pixels/thread).
//
// R2/R3 counters: top-5 dispatches are 41us harness d_ws poison fills at 82%
// HBM peak -> uncontrollable floor ~45-50us; this round targets the remaining
// ~25us of hl_partial VALU time.

#define HW    65536             // 256*256
#define NPIX  524288            // 8 * HW pixel positions
#define BLOCK 256
#define PXT   2                 // pixels per thread (adjacent -> float2 loads)
#define NBLK  (NPIX / (BLOCK * PXT))   // 1024

__device__ __forceinline__ void contrib(float v, float ivs, float go, float Ls,
                                        float& aW, float& aE) {
  float u  = (v + 1.0f) * 0.5f;     // matches reference rounding (add then mul)
  float g  = fmaf(u, ivs, go);      // (u+0.05)/step - 0.5
  float kf = floorf(g);
  float f  = g - kf;                // in [0,1), exact (|g| < 2^23)
  // candidate k0=kf: in-window iff f<0.5, weight 64-kf
  // candidate k0+1 : in-window iff f>0.5, weight 63-kf
  // at most one passes (disjoint tiling); f==0.5 -> neither (matches t>0 strict)
  float t0 = 0.5f - f;
  float t1 = f - 0.5f;
  bool in0 = (t0 > 0.0f) && (fabsf(kf - 31.5f) < 32.5f);  // kf in [0,63]
  bool in1 = (t1 > 0.0f) && (fabsf(kf - 30.5f) < 32.5f);  // kf in [-1,62]
  float w0 = in0 ? (64.0f - kf) : 0.0f;
  float w1 = in1 ? (63.0f - kf) : 0.0f;
  float z0 = t0 * Ls;               // z = ln(1.01f) * t,  t = step * t'
  float z1 = t1 * Ls;
  float e0 = fmaf(0.5f * z0, z0, z0);   // expm1(z), O(z^3) ~ 1e-13 dropped
  float e1 = fmaf(0.5f * z1, z1, z1);
  aW += w0 + w1;                    // exact integer part (f32-exact)
  aE  = fmaf(w0, e0, aE);
  aE  = fmaf(w1, e1, aE);
}

__global__ __launch_bounds__(BLOCK) void hl_partial(
    const float* __restrict__ img_in, const float* __restrict__ img_ref,
    double* __restrict__ partials) {
  __shared__ double redW[4], redE[4];

  // Replicate np.linspace(-0.05, 1.05, 65) step in f64, then cast constants.
  const double start = -0.05;
  const double step  = (1.05 - (-0.05)) / 64.0;
  const float  ivs = (float)(1.0 / step);            // 1/step
  const float  go  = (float)(0.05 / step - 0.5);     // (u+0.05)/step - 0.5 offset
  const float  Ls  = (float)(log((double)1.01f) * step);  // ln(f32(1.01)) * step

  // f32 YUV coefficients; f32 fma dot (reference einsum is f32)
  const float Y0 = 0.299f,    Y1 = 0.587f,    Y2 = 0.114f;
  const float U0 = -0.14713f, U1 = -0.28886f, U2 = 0.436f;
  const float V0 = 0.615f,    V1 = -0.51499f, V2 = -0.10001f;

  float aWp = 0.f, aWn = 0.f;   // + image / - image integer parts (f32-exact)
  float aEp = 0.f, aEn = 0.f;   // soft parts

  const int pair = blockIdx.x * BLOCK + threadIdx.x;   // 2 adjacent pixels
  const int p    = pair << 1;
  const int b    = p >> 16;              // batch (uniform per block: 512 | HW)
  const int hw   = p & (HW - 1);
  const float2* pi = (const float2*)(img_in  + (size_t)b * (3 * HW) + hw);
  const float2* pr = (const float2*)(img_ref + (size_t)b * (3 * HW) + hw);
  float2 r0 = pi[0], g0 = pi[HW / 2], b0 = pi[HW];     // strides in float2 units
  float2 r1 = pr[0], g1 = pr[HW / 2], b1 = pr[HW];

  const float rr0[2] = { r0.x, r0.y }, gg0[2] = { g0.x, g0.y }, bb0[2] = { b0.x, b0.y };
  const float rr1[2] = { r1.x, r1.y }, gg1[2] = { g1.x, g1.y }, bb1[2] = { b1.x, b1.y };

  #pragma unroll
  for (int i = 0; i < PXT; ++i) {
    float ri = rr0[i], gi = gg0[i], bi = bb0[i];
    float rj = rr1[i], gj = gg1[i], bj = bb1[i];

    // RGB
    contrib(ri, ivs, go, Ls, aWp, aEp);
    contrib(gi, ivs, go, Ls, aWp, aEp);
    contrib(bi, ivs, go, Ls, aWp, aEp);
    contrib(rj, ivs, go, Ls, aWn, aEn);
    contrib(gj, ivs, go, Ls, aWn, aEn);
    contrib(bj, ivs, go, Ls, aWn, aEn);

    // YUV in f32 (j-ascending fma chain like the einsum)
    float yi = fmaf(Y2, bi, fmaf(Y1, gi, Y0 * ri));
    float ui = fmaf(U2, bi, fmaf(U1, gi, U0 * ri));
    float vi = fmaf(V2, bi, fmaf(V1, gi, V0 * ri));
    float yj = fmaf(Y2, bj, fmaf(Y1, gj, Y0 * rj));
    float uj = fmaf(U2, bj, fmaf(U1, gj, U0 * rj));
    float vj = fmaf(V2, bj, fmaf(V1, gj, V0 * rj));

    contrib(yi, ivs, go, Ls, aWp, aEp);
    contrib(ui, ivs, go, Ls, aWp, aEp);
    contrib(vi, ivs, go, Ls, aWp, aEp);
    contrib(yj, ivs, go, Ls, aWn, aEn);
    contrib(uj, ivs, go, Ls, aWn, aEn);
    contrib(vj, ivs, go, Ls, aWn, aEn);
  }

  float  aW = aWp - aWn;                      // exact (integer-valued f32)
  double aE = (double)aEp - (double)aEn;

  // wave(64) shuffle reduction, then cross-wave via LDS
  #pragma unroll
  for (int off = 32; off > 0; off >>= 1) {
    aW += __shfl_down(aW, off);               // wave sum <= 98304: f32-exact
    aE += __shfl_down(aE, off);
  }
  int wv = threadIdx.x >> 6;
  if ((threadIdx.x & 63) == 0) { redW[wv] = (double)aW; redE[wv] = aE; }
  __syncthreads();

  if (threadIdx.x == 0) {
    double sW = 0.0, sE = 0.0;
    #pragma unroll
    for (int w = 0; w < 4; ++w) { sW += redW[w]; sE += redE[w]; }
    partials[2 * blockIdx.x]     = sW;  // unconditional store: no ws init needed
    partials[2 * blockIdx.x + 1] = sE;
  }
}

__global__ __launch_bounds__(BLOCK) void hl_final(
    const double* __restrict__ partials, float* __restrict__ out) {
  __shared__ double redW[4], redE[4];
  double sW = 0.0, sE = 0.0;
  for (int b = threadIdx.x; b < NBLK; b += BLOCK) {
    sW += partials[2 * b];
    sE += partials[2 * b + 1];
  }
  #pragma unroll
  for (int off = 32; off > 0; off >>= 1) {
    sW += __shfl_down(sW, off);
    sE += __shfl_down(sE, off);
  }
  int wv = threadIdx.x >> 6;
  if ((threadIdx.x & 63) == 0) { redW[wv] = sW; redE[wv] = sE; }
  __syncthreads();
  if (threadIdx.x == 0) {
    double tW = 0.0, tE = 0.0;
    #pragma unroll
    for (int w = 0; w < 4; ++w) { tW += redW[w]; tE += redE[w]; }
    out[0] = (float)((tW + tE) * (1.0 / (double)NPIX));
  }
}

extern "C" void kernel_launch(void* const* d_in, const int* in_sizes, int n_in,
                              void* d_out, int out_size, void* d_ws, size_t ws_size,
                              hipStream_t stream) {
  const float* img_in  = (const float*)d_in[0];
  const float* img_ref = (const float*)d_in[1];
  float* out = (float*)d_out;
  double* partials = (double*)d_ws;   // 2*NBLK doubles = 16 KB

  hl_partial<<<NBLK, BLOCK, 0, stream>>>(img_in, img_ref, partials);
  hl_final<<<1, BLOCK, 0, stream>>>(partials, out);
}